// Round 1
// baseline (153.679 us; speedup 1.0000x reference)
//
#include <hip/hip_runtime.h>
#include <hip/hip_bf16.h>

// Output row i (N = P*4 rows, D = 256 f32 each):
//   p = mapping[i]
//   last-of-group  <=> i == N-1 || mapping[i+1] != p
//   last  -> solvent_features[p]
//   else  -> monomer_features[i - p]   // running monomer rank = i - (#lasts before i) = i - p
// Pure memory-bound gather; vectorized as float4 (64 float4 per row).

__global__ void __launch_bounds__(256)
separated_gnn_gather(const float4* __restrict__ mono,   // [P*3 * 64] float4
                     const float4* __restrict__ solv,   // [P   * 64] float4
                     const int*    __restrict__ mapping, // [N]
                     float4*       __restrict__ out,    // [N * 64]
                     int n_rows)
{
    const long long total = (long long)n_rows * 64;     // float4 elements
    const long long stride = (long long)gridDim.x * blockDim.x;
    for (long long t = (long long)blockIdx.x * blockDim.x + threadIdx.x;
         t < total; t += stride) {
        const int i = (int)(t >> 6);      // output row
        const int c = (int)(t & 63);      // float4 column within row
        const int p = mapping[i];
        const bool last = (i + 1 == n_rows) || (mapping[i + 1] != p);
        const float4* __restrict__ src =
            last ? (solv + (long long)p * 64)
                 : (mono + (long long)(i - p) * 64);
        out[t] = src[c];
    }
}

extern "C" void kernel_launch(void* const* d_in, const int* in_sizes, int n_in,
                              void* d_out, int out_size, void* d_ws, size_t ws_size,
                              hipStream_t stream)
{
    const float4* mono    = (const float4*)d_in[0];   // monomer_features  [P*3, 256] f32
    const float4* solv    = (const float4*)d_in[1];   // solvent_features  [P,   256] f32
    const int*    mapping = (const int*)d_in[2];      // polymer_mapping   [N] int32
    float4*       out     = (float4*)d_out;           // [N, 256] f32

    const int n_rows = in_sizes[2];                   // N = 400000
    const long long total = (long long)n_rows * 64;   // float4 count

    const int block = 256;
    long long want = (total + block - 1) / block;
    int grid = (int)(want < 2048 ? want : 2048);      // grid-stride the rest

    separated_gnn_gather<<<grid, block, 0, stream>>>(mono, solv, mapping, out, n_rows);
}